// Round 1
// baseline (25.806 us; speedup 1.0000x reference)
//
#include <hip/hip_runtime.h>

// B-spline (degree 3, 16 control points, uniform knots linspace(-3,3,20)).
// out(x) = cubic polynomial in u = frac((x+3)/h), coefficients per interval j,
// where c(j) is a fixed linear combo of cp[j-3..j] (out-of-range cp -> 0).
// x < -3 or x >= 3 (incl. x==3 exactly) -> 0, matching the reference recursion.

#define N_CP   16
#define DEG    3
#define NKNOT  (N_CP + DEG + 1)   // 20
#define NINT   (NKNOT - 1)        // 19 intervals

__device__ __forceinline__ float eval_one(float xe, const float4* sc,
                                          float start, float inv_h) {
    float t = (xe - start) * inv_h;            // position in knot-index space
    bool in_range = (t >= 0.0f) & (t < (float)NINT);   // NaN-safe: false
    float fj = floorf(t);
    int j = (int)fj;
    j = j < 0 ? 0 : (j > NINT - 1 ? NINT - 1 : j);
    float u = t - fj;                          // fractional position in interval
    float4 c = sc[j];                          // ds_read_b128, 16B aligned
    float res = ((c.w * u + c.z) * u + c.y) * u + c.x;  // Horner
    return in_range ? res : 0.0f;
}

__global__ __launch_bounds__(256) void bspline_kernel(
    const float* __restrict__ x,
    const float* __restrict__ cp,
    float* __restrict__ out,
    int n)   // total elements (multiple of 4 handled vectorized + scalar tail)
{
    __shared__ float4 sc[NINT];

    // Per-block: build interval polynomial coefficients (19 float4).
    int tid = threadIdx.x;
    if (tid < NINT) {
        int j = tid;
        // p_m = cp[j-3+m], 0 if index outside [0, N_CP)
        float p0 = (j - 3 >= 0 && j - 3 < N_CP) ? cp[j - 3] : 0.0f;
        float p1 = (j - 2 >= 0 && j - 2 < N_CP) ? cp[j - 2] : 0.0f;
        float p2 = (j - 1 >= 0 && j - 1 < N_CP) ? cp[j - 1] : 0.0f;
        float p3 = (j     >= 0 && j     < N_CP) ? cp[j]     : 0.0f;
        // Uniform cubic B-spline basis expanded in powers of u:
        // w0=(1-u)^3/6, w1=(3u^3-6u^2+4)/6, w2=(-3u^3+3u^2+3u+1)/6, w3=u^3/6
        float c0 = (p0 + 4.0f * p1 + p2) * (1.0f / 6.0f);
        float c1 = (p2 - p0) * 0.5f;
        float c2 = (p0 - 2.0f * p1 + p2) * 0.5f;
        float c3 = (p3 - p0) * (1.0f / 6.0f) + (p1 - p2) * 0.5f;
        sc[j] = make_float4(c0, c1, c2, c3);
    }
    __syncthreads();

    const float start = -3.0f;
    const float inv_h = (float)NINT / 6.0f;    // 1/h, h = 6/19

    int n4 = n >> 2;
    const float4* x4 = (const float4*)x;
    float4* o4 = (float4*)out;

    int idx = blockIdx.x * blockDim.x + threadIdx.x;
    int stride = gridDim.x * blockDim.x;

    for (int i = idx; i < n4; i += stride) {
        float4 v = x4[i];
        float4 r;
        r.x = eval_one(v.x, sc, start, inv_h);
        r.y = eval_one(v.y, sc, start, inv_h);
        r.z = eval_one(v.z, sc, start, inv_h);
        r.w = eval_one(v.w, sc, start, inv_h);
        o4[i] = r;
    }

    // scalar tail (n not multiple of 4)
    int tail_start = n4 << 2;
    for (int i = tail_start + idx; i < n; i += stride) {
        out[i] = eval_one(x[i], sc, start, inv_h);
    }
}

extern "C" void kernel_launch(void* const* d_in, const int* in_sizes, int n_in,
                              void* d_out, int out_size, void* d_ws, size_t ws_size,
                              hipStream_t stream) {
    const float* x  = (const float*)d_in[0];
    const float* cp = (const float*)d_in[1];
    // d_in[2] = knots (uniform linspace(-3,3,20); geometry hardcoded per module constants)
    float* out = (float*)d_out;

    int n = in_sizes[0];
    int n4 = n >> 2;
    int blocks = (n4 + 255) / 256;
    if (blocks > 2048) blocks = 2048;
    if (blocks < 1) blocks = 1;

    bspline_kernel<<<blocks, 256, 0, stream>>>(x, cp, out, n);
}